// Round 3
// baseline (705.312 us; speedup 1.0000x reference)
//
#include <hip/hip_runtime.h>
#include <cstddef>

#define TT 1024
#define BB 512
#define FAN 136        // D + H
#define ZSTRIDE 6144   // floats per t-slab: 64 octets x 96
#define FLAGOFF 6142   // pad word inside each t-slab used as ready flag
#define NRECB 16       // recurrence blocks (x512 threads)
#define DEPTH 16       // prefetch ring depth (steps)

// ---------- fast transcendentals (raw gfx950 VOP1) ----------
__device__ __forceinline__ float v_exp2 (float x){ float d; asm("v_exp_f32 %0, %1"   : "=v"(d) : "v"(x)); return d; }
__device__ __forceinline__ float v_rcp  (float x){ float d; asm("v_rcp_f32 %0, %1"   : "=v"(d) : "v"(x)); return d; }
__device__ __forceinline__ float v_cosr (float x){ float d; asm("v_cos_f32 %0, %1"   : "=v"(d) : "v"(x)); return d; }
__device__ __forceinline__ float v_fract(float x){ float d; asm("v_fract_f32 %0, %1" : "=v"(d) : "v"(x)); return d; }

__device__ __forceinline__ float fast_cos(float x){
    return v_cosr(v_fract(x * 0.15915494309189535f));   // v_cos takes revolutions
}

// ---------- cross-lane helpers ----------
// DPP quad_perm xor1=0xB1, xor2=0x4E, xor3=0x1B, row_half_mirror(xor7)=0x141
template<int CTRL>
__device__ __forceinline__ float dppf(float x){
    return __int_as_float(__builtin_amdgcn_mov_dpp(__float_as_int(x), CTRL, 0xF, 0xF, true));
}
// ds_swizzle BitMode: src_lane = ((lane & and) | or) ^ xor ; offset = xor<<10 | or<<5 | and
template<int PAT>
__device__ __forceinline__ float swzf(float x){
    return __int_as_float(__builtin_amdgcn_ds_swizzle(__float_as_int(x), PAT));
}

// ---------------------------------------------------------------------------
// init: zero the 1024 per-t ready flags (ws is poisoned 0xAA before each call)
// ---------------------------------------------------------------------------
__global__ __launch_bounds__(1024) void qlstm_init(unsigned* zw){
    zw[(size_t)threadIdx.x * ZSTRIDE + FLAGOFF] = 0u;
}

// ---------------------------------------------------------------------------
// fused kernel: blocks [0,16) = recurrence role, blocks [16,1040) = zx role.
// zx block (bid-16 = t): computes Z[t] (x-part of all gate preacts + bias),
// then release-stores flag[t]=1. rec blocks consume Z[t] gated by flags,
// with a 16-step register prefetch ring.
// ---------------------------------------------------------------------------
__global__ __launch_bounds__(512) void qlstm_fused(
    const float* __restrict__ x,    // [T][B][128]
    const float* __restrict__ Wf, const float* __restrict__ bf,
    const float* __restrict__ Wi, const float* __restrict__ bi,
    const float* __restrict__ Wu, const float* __restrict__ bu,
    const float* __restrict__ Wo, const float* __restrict__ bo,
    const float* __restrict__ qwf, const float* __restrict__ qwi,
    const float* __restrict__ qwo,
    float* __restrict__ Z,          // [T][64][96] (+ flag word per slab)
    float* __restrict__ out)        // [T][B][8] ++ hx[B][8] ++ cx[B][8]
{
    const int bid = blockIdx.x;
    const int tid = threadIdx.x;
    unsigned* zw = (unsigned*)Z;

    if (bid >= NRECB) {
        // ------------------------- zx role: one t per block -------------------
        const int t  = bid - NRECB;
        const int bl = tid >> 4;        // 0..31 batch rows per pass
        const int ds = tid & 15;        // d-slice of 8

        float w[11][8];
        #pragma unroll
        for (int k = 0; k < 8; ++k) {
            const float4 lo = *reinterpret_cast<const float4*>(Wu + k * FAN + ds * 8);
            const float4 hi = *reinterpret_cast<const float4*>(Wu + k * FAN + ds * 8 + 4);
            w[k][0]=lo.x; w[k][1]=lo.y; w[k][2]=lo.z; w[k][3]=lo.w;
            w[k][4]=hi.x; w[k][5]=hi.y; w[k][6]=hi.z; w[k][7]=hi.w;
        }
        {
            const float4 lo = *reinterpret_cast<const float4*>(Wf + ds * 8);
            const float4 hi = *reinterpret_cast<const float4*>(Wf + ds * 8 + 4);
            w[8][0]=lo.x; w[8][1]=lo.y; w[8][2]=lo.z; w[8][3]=lo.w;
            w[8][4]=hi.x; w[8][5]=hi.y; w[8][6]=hi.z; w[8][7]=hi.w;
        }
        {
            const float4 lo = *reinterpret_cast<const float4*>(Wi + ds * 8);
            const float4 hi = *reinterpret_cast<const float4*>(Wi + ds * 8 + 4);
            w[9][0]=lo.x; w[9][1]=lo.y; w[9][2]=lo.z; w[9][3]=lo.w;
            w[9][4]=hi.x; w[9][5]=hi.y; w[9][6]=hi.z; w[9][7]=hi.w;
        }
        {
            const float4 lo = *reinterpret_cast<const float4*>(Wo + ds * 8);
            const float4 hi = *reinterpret_cast<const float4*>(Wo + ds * 8 + 4);
            w[10][0]=lo.x; w[10][1]=lo.y; w[10][2]=lo.z; w[10][3]=lo.w;
            w[10][4]=hi.x; w[10][5]=hi.y; w[10][6]=hi.z; w[10][7]=hi.w;
        }

        float my_bias = 0.f;
        if (ds <  8) my_bias = bu[ds];
        if (ds ==  8) my_bias = bf[0];
        if (ds ==  9) my_bias = bi[0];
        if (ds == 10) my_bias = bo[0];

        const float* xp = x + ((size_t)t * BB + bl) * 128 + ds * 8;
        float* zt = Z + (size_t)t * ZSTRIDE;

        for (int it = 0; it < 16; ++it) {
            const int b = it * 32 + bl;
            const float4 xa = *reinterpret_cast<const float4*>(xp);
            const float4 xb = *reinterpret_cast<const float4*>(xp + 4);
            const float xr[8] = {xa.x, xa.y, xa.z, xa.w, xb.x, xb.y, xb.z, xb.w};

            float acc[11];
            #pragma unroll
            for (int k = 0; k < 11; ++k) {
                float s = 0.f;
                #pragma unroll
                for (int e = 0; e < 8; ++e) s = fmaf(xr[e], w[k][e], s);
                acc[k] = s;
            }
            #pragma unroll
            for (int k = 0; k < 11; ++k) {
                float v = acc[k];
                v += dppf<0xB1>(v);      // xor1
                v += dppf<0x4E>(v);      // xor2
                v += swzf<0x101F>(v);    // xor4
                v += swzf<0x201F>(v);    // xor8
                acc[k] = v;
            }
            float val = acc[0];
            #pragma unroll
            for (int k = 1; k < 11; ++k) val = (ds == k) ? acc[k] : val;
            val += my_bias;
            if (ds < 11)
                zt[(b >> 3) * 96 + ds * 8 + (b & 7)] = val;

            xp += 32 * 128;
        }

        __syncthreads();
        if (tid == 0)
            __hip_atomic_store(zw + (size_t)t * ZSTRIDE + FLAGOFF, 1u,
                               __ATOMIC_RELEASE, __HIP_MEMORY_SCOPE_AGENT);
        return;
    }

    // --------------------------- rec role ------------------------------------
    // 16 lanes per chain: lane r<8 owns g-row r (and h[r],c[r]); r=8,9,10 own
    // f,i,o; r=11..15 idle-but-uniform. 32 chains per block.
    const int cid = tid >> 4;           // chain within block
    const int r   = tid & 15;
    const int b   = bid * 32 + cid;     // batch chain id
    const int j   = r & 7;
    const bool isg = (r < 8);
    const int rw  = (r < 11) ? r : 11;  // clamped row for z-load addressing

    // XOR-paired recurrent weights: wt[m] pairs with a[m] = h[j^m]
    const float* Wrow = (r < 8) ? (Wu + r * FAN)
                      : (r == 8) ? Wf : (r == 9) ? Wi : Wo;
    float wt[8];
    #pragma unroll
    for (int m = 0; m < 8; ++m)
        wt[m] = (r < 11) ? Wrow[128 + (j ^ m)] : 0.f;

    // unified activation constants:
    //   g lanes:  tanh(d)             = fma(rcp(1+exp2(d*2log2e)), -2, 1)
    //   fio lanes: sigmoid(cos(d)*cq) = rcp(1+exp2(cos(d)*(-cq*log2e)))
    const float LOG2E = 1.4426950408889634f;
    float kq = 2.0f * LOG2E, mm = -2.0f, dd = 1.0f;
    if (!isg) { mm = 1.0f; dd = 0.0f; }
    if (r == 8)  kq = -LOG2E * fast_cos(qwf[0]);
    if (r == 9)  kq = -LOG2E * fast_cos(qwi[0]);
    if (r == 10) kq = -LOG2E * fast_cos(qwo[0]);
    if (r >  10) kq = -LOG2E;

    const float* zcol = Z + (size_t)(b >> 3) * 96 + rw * 8 + (b & 7);

    // bounded acquire-poll on flag[tw] (each of the 16 lanes polls one t)
    auto waitflag = [&](int tw) {
        int it = 0;
        while (__hip_atomic_load(zw + (size_t)tw * ZSTRIDE + FLAGOFF,
                                 __ATOMIC_ACQUIRE, __HIP_MEMORY_SCOPE_AGENT) != 1u) {
            __builtin_amdgcn_s_sleep(8);
            if (++it > (1 << 17)) break;     // bail: wrong-but-terminates
        }
    };

    waitflag(r);                         // flags 0..15
    float zr[DEPTH];
    #pragma unroll
    for (int p = 0; p < DEPTH; ++p) zr[p] = zcol[(size_t)p * ZSTRIDE];

    float a[8];
    #pragma unroll
    for (int m = 0; m < 8; ++m) a[m] = 0.f;
    float c = 0.f, hb = 0.f;

    float* op = out + (size_t)b * 8 + j;

    for (int t0 = 0; t0 < TT; t0 += DEPTH) {
        if (t0 + DEPTH < TT) waitflag(t0 + DEPTH + r);
        #pragma unroll
        for (int p = 0; p < DEPTH; ++p) {
            const int t = t0 + p;
            float d = zr[p];
            const int tn = t0 + DEPTH + p;           // refill slot p
            if (tn < TT) zr[p] = zcol[(size_t)tn * ZSTRIDE];

            #pragma unroll
            for (int m = 0; m < 8; ++m) d = fmaf(a[m], wt[m], d);

            const float cz  = fast_cos(d);
            const float arg = (isg ? d : cz) * kq;
            const float val = fmaf(v_rcp(1.0f + v_exp2(arg)), mm, dd);

            const float fg = swzf<0x110>(val);       // lane (grp16|8): f
            const float ig = swzf<0x130>(val);       // lane (grp16|9): i
            const float og = swzf<0x150>(val);       // lane (grp16|10): o

            c = fmaf(fg, c, ig * val);               // val = g on r<8 lanes
            const float e2 = v_exp2(c * (2.0f * LOG2E));
            const float tc = fmaf(v_rcp(1.0f + e2), -2.0f, 1.0f);
            const float h  = og * tc;

            if (r < 8) op[(size_t)t * 4096] = h;

            hb = swzf<0x017>(h);                     // fold lanes 8-15 <- 0-7
            a[0] = hb;
            a[1] = dppf<0xB1>(hb);
            a[2] = dppf<0x4E>(hb);
            a[3] = dppf<0x1B>(hb);
            const float h7 = dppf<0x141>(hb);
            a[7] = h7;
            a[6] = dppf<0xB1>(h7);
            a[5] = dppf<0x4E>(h7);
            a[4] = dppf<0x1B>(h7);
        }
    }

    if (r < 8) {
        out[4194304 + (size_t)b * 8 + j] = hb;   // hx
        out[4198400 + (size_t)b * 8 + j] = c;    // cx
    }
}

// ---------------------------------------------------------------------------
extern "C" void kernel_launch(void* const* d_in, const int* in_sizes, int n_in,
                              void* d_out, int out_size, void* d_ws, size_t ws_size,
                              hipStream_t stream) {
    const float* x   = (const float*)d_in[0];
    const float* Wf  = (const float*)d_in[1];
    const float* bf  = (const float*)d_in[2];
    const float* Wi  = (const float*)d_in[3];
    const float* bi  = (const float*)d_in[4];
    const float* Wu  = (const float*)d_in[5];
    const float* bu  = (const float*)d_in[6];
    const float* Wo  = (const float*)d_in[7];
    const float* bo  = (const float*)d_in[8];
    const float* qwf = (const float*)d_in[9];
    const float* qwi = (const float*)d_in[10];
    // d_in[11] = qwu: unused (g-gate has no quantum circuit in the reference)
    const float* qwo = (const float*)d_in[12];
    float* out = (float*)d_out;
    float* Z   = (float*)d_ws;      // [1024][6144] f32 = 25.2 MB (flags in pad)

    qlstm_init<<<1, 1024, 0, stream>>>((unsigned*)Z);
    qlstm_fused<<<NRECB + TT, 512, 0, stream>>>(
        x, Wf, bf, Wi, bi, Wu, bu, Wo, bo, qwf, qwi, qwo, Z, out);
}